// Round 6
// baseline (422.138 us; speedup 1.0000x reference)
//
#include <hip/hip_runtime.h>
#include <hip/hip_bf16.h>
#include <stdint.h>

#define B_   2
#define S_   2048
#define H_   2048
#define NH_  16
#define HD_  128
#define MTOT (B_*S_)   // 4096

typedef __attribute__((ext_vector_type(8))) short bf16x8;   // 8 bf16 = 4 VGPRs
typedef __attribute__((ext_vector_type(4))) float f32x4;    // MFMA C/D

__device__ __forceinline__ void gload_lds16(const void* g, void* l) {
    __builtin_amdgcn_global_load_lds(
        (const __attribute__((address_space(1))) void*)g,
        (__attribute__((address_space(3))) void*)l, 16, 0, 0);
}

__device__ __forceinline__ unsigned short f2bfu(float x) {
    __hip_bfloat16 h = __float2bfloat16(x);
    return *reinterpret_cast<unsigned short*>(&h);
}
__device__ __forceinline__ int packbf(float a, float b) {
    return (int)f2bfu(a) | ((int)f2bfu(b) << 16);
}

// ---------------------------------------------------------------- casts fp32 -> bf16
__global__ void castk(const float* __restrict__ in, __hip_bfloat16* __restrict__ out, int n4) {
    int i = blockIdx.x * 256 + threadIdx.x;
    if (i < n4) {
        float4 v = *(const float4*)(in + (size_t)i * 4);
        out[(size_t)i*4 + 0] = __float2bfloat16(v.x);
        out[(size_t)i*4 + 1] = __float2bfloat16(v.y);
        out[(size_t)i*4 + 2] = __float2bfloat16(v.z);
        out[(size_t)i*4 + 3] = __float2bfloat16(v.w);
    }
}

__global__ void castw4(const float* __restrict__ w0, const float* __restrict__ w1,
                       const float* __restrict__ w2, const float* __restrict__ w3,
                       __hip_bfloat16* o0, __hip_bfloat16* o1,
                       __hip_bfloat16* o2, __hip_bfloat16* o3, int n4) {
    const float* in; __hip_bfloat16* out;
    switch (blockIdx.y) {
        case 0:  in = w0; out = o0; break;
        case 1:  in = w1; out = o1; break;
        case 2:  in = w2; out = o2; break;
        default: in = w3; out = o3; break;
    }
    int i = blockIdx.x * 256 + threadIdx.x;
    if (i < n4) {
        float4 v = *(const float4*)(in + (size_t)i * 4);
        out[(size_t)i*4 + 0] = __float2bfloat16(v.x);
        out[(size_t)i*4 + 1] = __float2bfloat16(v.y);
        out[(size_t)i*4 + 2] = __float2bfloat16(v.z);
        out[(size_t)i*4 + 3] = __float2bfloat16(v.w);
    }
}

// ---------------------------------------------------------------- NT-GEMM body (m97 structure)
// BF16OUT=1: bf16 row-major out, or (vt=true) transposed per-head V^T[(b*16+bc)*128+d][s]
// BF16OUT=0: fp32 row-major out
template<int SMEMB, int BF16OUT>
__device__ __forceinline__ void gemm_body(const __hip_bfloat16* __restrict__ Ablk,
                                          const __hip_bfloat16* __restrict__ Wblk,
                                          const float* __restrict__ bias,
                                          void* __restrict__ Cout,
                                          int N, int K, int br, int bc, bool vt)
{
    __shared__ __align__(16) char smem[SMEMB];
    __hip_bfloat16* As = (__hip_bfloat16*)smem;             // 128x32, 8192 B
    __hip_bfloat16* Bs = (__hip_bfloat16*)(smem + 8192);    // 128x32, 8192 B

    const int tid  = threadIdx.x;
    const int wave = tid >> 6, lane = tid & 63;
    const int quad = lane >> 4, l16 = lane & 15;
    const int wr = wave >> 1, wc = wave & 1;

    f32x4 acc[4][4] = {};

    for (int k0 = 0; k0 < K; k0 += 32) {
#pragma unroll
        for (int t = 0; t < 2; ++t) {
            int c = t * 256 + wave * 64 + lane;
            int row = c >> 2, cc = c & 3;
            int base = (t * 256 + wave * 64) * 16;       // wave-uniform
            gload_lds16(Ablk + (size_t)row * K + k0 + cc * 8, (char*)As + base);
            gload_lds16(Wblk + (size_t)row * K + k0 + cc * 8, (char*)Bs + base);
        }
        __syncthreads();

        bf16x8 af[4], bf[4];
#pragma unroll
        for (int i = 0; i < 4; ++i)
            af[i] = *(const bf16x8*)&As[(wr * 64 + i * 16 + l16) * 32 + quad * 8];
#pragma unroll
        for (int j = 0; j < 4; ++j)
            bf[j] = *(const bf16x8*)&Bs[(wc * 64 + j * 16 + l16) * 32 + quad * 8];

#pragma unroll
        for (int i = 0; i < 4; ++i)
#pragma unroll
            for (int j = 0; j < 4; ++j)
                acc[i][j] = __builtin_amdgcn_mfma_f32_16x16x32_bf16(af[i], bf[j], acc[i][j], 0, 0, 0);
        __syncthreads();
    }

    if (BF16OUT && vt) {
        // ---- transposed epilogue: store V^T[(bq*16+bc)*128 + d][s] via LDS 128x136
        __hip_bfloat16* Ls = (__hip_bfloat16*)smem;   // 128*136*2 = 34816 B
#pragma unroll
        for (int j = 0; j < 4; ++j) {
            int d = wc * 64 + j * 16 + l16;
            float bv = bias[bc * 128 + d];
#pragma unroll
            for (int i = 0; i < 4; ++i) {
                int t0 = wr * 64 + i * 16 + quad * 4;
#pragma unroll
                for (int r = 0; r < 4; ++r)
                    Ls[d * 136 + t0 + r] = __float2bfloat16(acc[i][j][r] + bv);
            }
        }
        __syncthreads();
        const int bq = br >> 4;                  // batch
        const int s0 = (br & 15) * 128;          // token offset within batch
        __hip_bfloat16* VT = (__hip_bfloat16*)Cout;
        const size_t rowbase = (size_t)(bq * 16 + bc) * 128;
#pragma unroll
        for (int rep = 0; rep < 8; ++rep) {
            int L = rep * 256 + tid;             // 0..2047
            int d = L >> 4, tch = L & 15;
            bf16x8 v = *(const bf16x8*)&Ls[d * 136 + tch * 8];
            *(bf16x8*)(VT + (rowbase + d) * (size_t)S_ + s0 + tch * 8) = v;
        }
        return;
    }

    // ---- row-major epilogue
#pragma unroll
    for (int i = 0; i < 4; ++i) {
        int row = br * 128 + wr * 64 + i * 16 + quad * 4;
#pragma unroll
        for (int j = 0; j < 4; ++j) {
            int col = bc * 128 + wc * 64 + j * 16 + l16;
            float bv = bias[col];
#pragma unroll
            for (int r = 0; r < 4; ++r) {
                float v = acc[i][j][r] + bv;
                if (BF16OUT)
                    ((__hip_bfloat16*)Cout)[(size_t)(row + r) * N + col] = __float2bfloat16(v);
                else
                    ((float*)Cout)[(size_t)(row + r) * N + col] = v;
            }
        }
    }
}

// fused Q/K/V projection: grid (48, 32); V written transposed per head
__global__ __launch_bounds__(256)
void gemm_qkv(const __hip_bfloat16* __restrict__ X,
              const __hip_bfloat16* __restrict__ Wq, const __hip_bfloat16* __restrict__ Wk,
              const __hip_bfloat16* __restrict__ Wv,
              const float* __restrict__ bq, const float* __restrict__ bk,
              const float* __restrict__ bv,
              __hip_bfloat16* Qo, __hip_bfloat16* Ko, __hip_bfloat16* VTo)
{
    const int sel = blockIdx.x >> 4;     // 0,1,2
    const int bc  = blockIdx.x & 15;
    const int br  = blockIdx.y;
    const __hip_bfloat16* W = (sel == 0) ? Wq : (sel == 1) ? Wk : Wv;
    const float* bias       = (sel == 0) ? bq : (sel == 1) ? bk : bv;
    void* out               = (sel == 0) ? (void*)Qo : (sel == 1) ? (void*)Ko : (void*)VTo;
    gemm_body<34816, 1>(X + (size_t)(br * 128) * H_, W + (size_t)(bc * 128) * H_,
                        bias, out, H_, H_, br, bc, sel == 2);
}

// O-projection: fp32 out
__global__ __launch_bounds__(256)
void gemm_out(const __hip_bfloat16* __restrict__ A, const __hip_bfloat16* __restrict__ W,
              const float* __restrict__ bias, float* __restrict__ C)
{
    gemm_body<16384, 0>(A + (size_t)(blockIdx.y * 128) * H_, W + (size_t)(blockIdx.x * 128) * H_,
                        bias, C, H_, H_, blockIdx.y, blockIdx.x, false);
}

// ---------------------------------------------------------------- flash attention v6
// Full-DMA double-buffered K and V^T staging, ONE barrier per K-iteration.
// S^T orientation, per-lane softmax, P transform via ds_bpermute (no LDS Ps).
__global__ __launch_bounds__(256)
void attn_kernel(const __hip_bfloat16* __restrict__ Q,
                 const __hip_bfloat16* __restrict__ K,
                 const __hip_bfloat16* __restrict__ VT,   // [(b*16+h)*128 + d][s]
                 __hip_bfloat16* __restrict__ O)
{
    // 16B-chunk XOR swizzle, DMA-compatible (unpadded), conflict-free b128 reads
    __shared__ __align__(16) char KsB[2][16384];   // K-tile: 64 key-rows x 256B
    __shared__ __align__(16) char VtB[2][16384];   // V^T-tile: 128 d-rows x 128B
    // total 65536 B

    const int tid  = threadIdx.x;
    const int wave = tid >> 6, lane = tid & 63;
    const int quad = lane >> 4, l16 = lane & 15;

    // XCD-pinning: all 16 blocks of one (b,h) on one XCD (RR heuristic)
    const int lid  = blockIdx.x;                 // 0..511
    const int xcd  = lid & 7;
    const int slot = lid >> 3;                   // 0..63
    const int bh   = ((slot >> 4) << 3) | xcd;   // 0..31
    const int pr   = slot & 15;                  // pair index 0..15
    const int b    = bh >> 4, h = bh & 15;

    const size_t headoff = (size_t)b * S_ * H_ + (size_t)h * HD_;
    const __hip_bfloat16* Qp = Q + headoff;
    const __hip_bfloat16* Kp = K + headoff;
    const __hip_bfloat16* Vtp = VT + (size_t)(b * 16 + h) * 128 * S_;

    const float scale = 0.08838834764831843f;    // 1/sqrt(128)
    // bpermute lane addresses for the P C->A transform
    const int A0 = (((quad & 1) * 2) * 16 + l16) * 4;
    const int A1 = A0 + 64;
    const bool hiq = (quad >= 2);

    for (int which = 0; which < 2; ++which) {
        const int qb = which ? pr : 31 - pr;     // disjoint pair: 33 iters total
        const int qrow_local = wave * 16;
        const int qrow = qb * 64 + qrow_local;

        bf16x8 qf[4];
#pragma unroll
        for (int kd = 0; kd < 4; ++kd)
            qf[kd] = *(const bf16x8*)(Qp + (size_t)(qrow + l16) * H_ + kd * 32 + quad * 8);

        f32x4 oacc[8] = {};
        float mi = -1e30f, li = 0.0f;            // per-lane: query qrow + l16
        int bb = 0;

        // ---- prologue: DMA tile 0 into buffer 0 (barrier of previous q-tile protects)
#pragma unroll
        for (int t = 0; t < 4; ++t) {
            int c = wave * 256 + t * 64 + lane;
            int krow = c >> 4, kpos = c & 15;
            gload_lds16(Kp + (size_t)krow * H_ + (kpos ^ (krow & 7)) * 8,
                        &KsB[0][(wave * 256 + t * 64) * 16]);
            int vrow = c >> 3, vpos = c & 7;
            gload_lds16(Vtp + (size_t)vrow * S_ + (vpos ^ (vrow & 7)) * 8,
                        &VtB[0][(wave * 256 + t * 64) * 16]);
        }
        __syncthreads();   // drains DMA (vmcnt) -> tile 0 ready

        for (int kb = 0; kb <= qb; ++kb) {
            const int nb = bb ^ 1;
            if (kb < qb) {   // async prefetch next tile; drained at this iter's end barrier
                const __hip_bfloat16* Kn = Kp + (size_t)(kb + 1) * 64 * H_;
                const int vcol = (kb + 1) * 64;
#pragma unroll
                for (int t = 0; t < 4; ++t) {
                    int c = wave * 256 + t * 64 + lane;
                    int krow = c >> 4, kpos = c & 15;
                    gload_lds16(Kn + (size_t)krow * H_ + (kpos ^ (krow & 7)) * 8,
                                &KsB[nb][(wave * 256 + t * 64) * 16]);
                    int vrow = c >> 3, vpos = c & 7;
                    gload_lds16(Vtp + (size_t)vrow * S_ + vcol + (vpos ^ (vrow & 7)) * 8,
                                &VtB[nb][(wave * 256 + t * 64) * 16]);
                }
            }

            // ---- S^T tile: D[key][query] = K·Q^T ; A = K-frag, B = Q-frag
            f32x4 sacc[4] = {};
#pragma unroll
            for (int cb = 0; cb < 4; ++cb) {
#pragma unroll
                for (int kd = 0; kd < 4; ++kd) {
                    int row = cb * 16 + l16;
                    int pos = (4 * kd + quad) ^ (l16 & 7);
                    bf16x8 kf = *(const bf16x8*)&KsB[bb][row * 256 + pos * 16];
                    sacc[cb] = __builtin_amdgcn_mfma_f32_16x16x32_bf16(kf, qf[kd], sacc[cb], 0, 0, 0);
                }
            }

            // lane owns query (qrow + l16); its 16 scores: keys cb*16 + quad*4 + r
            const bool diag = (kb == qb);
            float p[4][4];
            float tm = -1e30f;
#pragma unroll
            for (int cb = 0; cb < 4; ++cb)
#pragma unroll
                for (int r = 0; r < 4; ++r) {
                    float s = sacc[cb][r] * scale;
                    if (diag) {
                        int keyl = cb * 16 + quad * 4 + r;
                        if (keyl > qrow_local + l16) s = -1e30f;
                    }
                    p[cb][r] = s;
                    tm = fmaxf(tm, s);
                }
            tm = fmaxf(tm, __shfl_xor(tm, 16));
            tm = fmaxf(tm, __shfl_xor(tm, 32));
            float mnew = fmaxf(mi, tm);
            float sum = 0.0f;
#pragma unroll
            for (int cb = 0; cb < 4; ++cb)
#pragma unroll
                for (int r = 0; r < 4; ++r) {
                    float e = __expf(p[cb][r] - mnew);
                    p[cb][r] = e;
                    sum += e;
                }
            sum += __shfl_xor(sum, 16);
            sum += __shfl_xor(sum, 32);
            float alpha = __expf(mi - mnew);
            li = li * alpha + sum;
            mi = mnew;

            // rescale O (C-layout: reg r = query quad*4+r)
            float ar[4];
#pragma unroll
            for (int r = 0; r < 4; ++r)
                ar[r] = __shfl(alpha, quad * 4 + r);
#pragma unroll
            for (int db = 0; db < 8; ++db)
#pragma unroll
                for (int r = 0; r < 4; ++r)
                    oacc[db][r] *= ar[r];

            // ---- P C-layout -> A-layout via ds_bpermute (no LDS):
            // target dword v of frag ks = keys {ks*32+quad*8+2v, +1}
            // src lane = ((quad&1)*2 + (v>>1))*16 + l16 ; src reg = Pp[2ks+(quad>>1)][v&1]
            int Pp[4][2];
#pragma unroll
            for (int cb = 0; cb < 4; ++cb) {
                Pp[cb][0] = packbf(p[cb][0], p[cb][1]);
                Pp[cb][1] = packbf(p[cb][2], p[cb][3]);
            }
            bf16x8 pf[2];
#pragma unroll
            for (int ks = 0; ks < 2; ++ks) {
                int c0 = 2 * ks, c1 = 2 * ks + 1;
                int d0 = __builtin_amdgcn_ds_bpermute(A0, Pp[c0][0]);
                int e0 = __builtin_amdgcn_ds_bpermute(A0, Pp[c1][0]);
                int d1 = __builtin_amdgcn_ds_bpermute(A0, Pp[c0][1]);
                int e1 = __builtin_amdgcn_ds_bpermute(A0, Pp[c1][1]);
                int d2 = __builtin_amdgcn_ds_bpermute(A1, Pp[c0][0]);
                int e2 = __builtin_amdgcn_ds_bpermute(A1, Pp[c1][0]);
                int d3 = __builtin_amdgcn_ds_bpermute(A1, Pp[c0][1]);
                int e3 = __builtin_amdgcn_ds_bpermute(A1, Pp[c1][1]);
                union { int i[4]; bf16x8 v; } u;
                u.i[0] = hiq ? e0 : d0;
                u.i[1] = hiq ? e1 : d1;
                u.i[2] = hiq ? e2 : d2;
                u.i[3] = hiq ? e3 : d3;
                pf[ks] = u.v;
            }

            // ---- O += P @ V : B = V^T frag from swizzled VtB
#pragma unroll
            for (int ks = 0; ks < 2; ++ks) {
#pragma unroll
                for (int db = 0; db < 8; ++db) {
                    int vrow = db * 16 + l16;
                    int vpos = (ks * 4 + quad) ^ (l16 & 7);
                    bf16x8 vf = *(const bf16x8*)&VtB[bb][vrow * 128 + vpos * 16];
                    oacc[db] = __builtin_amdgcn_mfma_f32_16x16x32_bf16(pf[ks], vf, oacc[db], 0, 0, 0);
                }
            }

            __syncthreads();   // readers done with bb; drains prefetch DMA -> nb ready
            bb = nb;
        }

        // ---- epilogue: O[query=qrow+quad*4+r][d=db*16+l16]
        float lr[4];
#pragma unroll
        for (int r = 0; r < 4; ++r)
            lr[r] = __shfl(li, quad * 4 + r);
#pragma unroll
        for (int db = 0; db < 8; ++db)
#pragma unroll
            for (int r = 0; r < 4; ++r) {
                float v = oacc[db][r] / lr[r];
                size_t row = (size_t)b * S_ + qrow + quad * 4 + r;
                O[row * H_ + h * HD_ + db * 16 + l16] = __float2bfloat16(v);
            }
        // next which's prologue DMA is safe: last iter's barrier ensured all reads done
    }
}

// ---------------------------------------------------------------- launcher
extern "C" void kernel_launch(void* const* d_in, const int* in_sizes, int n_in,
                              void* d_out, int out_size, void* d_ws, size_t ws_size,
                              hipStream_t stream)
{
    const float* hs = (const float*)d_in[0];
    const float* Wq = (const float*)d_in[2];
    const float* bq = (const float*)d_in[3];
    const float* Wk = (const float*)d_in[4];
    const float* bk = (const float*)d_in[5];
    const float* Wv = (const float*)d_in[6];
    const float* bv = (const float*)d_in[7];
    const float* Wo = (const float*)d_in[8];
    const float* bo = (const float*)d_in[9];

    const size_t szX = (size_t)MTOT * H_;
    const size_t szW = (size_t)H_ * H_;

    __hip_bfloat16* Xbf = (__hip_bfloat16*)d_ws;   // reused as attention output
    __hip_bfloat16* Wqb = Xbf + szX;
    __hip_bfloat16* Wkb = Wqb + szW;
    __hip_bfloat16* Wvb = Wkb + szW;
    __hip_bfloat16* Wob = Wvb + szW;
    __hip_bfloat16* Qb  = Wob + szW;
    __hip_bfloat16* Kb  = Qb + szX;
    __hip_bfloat16* VTb = Kb + szX;                // V^T [(b*16+h)*128+d][s]

    castk<<<(int)((szX/4 + 255)/256), 256, 0, stream>>>(hs, Xbf, (int)(szX/4));
    dim3 wgrid((unsigned)((szW/4 + 255)/256), 4);
    castw4<<<wgrid, 256, 0, stream>>>(Wq, Wk, Wv, Wo, Wqb, Wkb, Wvb, Wob, (int)(szW/4));

    gemm_qkv<<<dim3(48, 32), 256, 0, stream>>>(Xbf, Wqb, Wkb, Wvb, bq, bk, bv, Qb, Kb, VTb);

    attn_kernel<<<dim3(512), 256, 0, stream>>>(Qb, Kb, VTb, Xbf);

    gemm_out<<<dim3(16, 32), 256, 0, stream>>>(Xbf, Wob, bo, (float*)d_out);
}

// Round 7
// 413.598 us; speedup vs baseline: 1.0206x; 1.0206x over previous
//
#include <hip/hip_runtime.h>
#include <hip/hip_bf16.h>
#include <stdint.h>

#define B_   2
#define S_   2048
#define H_   2048
#define NH_  16
#define HD_  128
#define MTOT (B_*S_)   // 4096

typedef __attribute__((ext_vector_type(8))) short bf16x8;   // 8 bf16 = 4 VGPRs
typedef __attribute__((ext_vector_type(4))) float f32x4;    // MFMA C/D

__device__ __forceinline__ void gload_lds16(const void* g, void* l) {
    __builtin_amdgcn_global_load_lds(
        (const __attribute__((address_space(1))) void*)g,
        (__attribute__((address_space(3))) void*)l, 16, 0, 0);
}

__device__ __forceinline__ unsigned short f2bfu(float x) {
    __hip_bfloat16 h = __float2bfloat16(x);
    return *reinterpret_cast<unsigned short*>(&h);
}
__device__ __forceinline__ int packbf(float a, float b) {
    return (int)f2bfu(a) | ((int)f2bfu(b) << 16);
}

// ---------------------------------------------------------------- casts fp32 -> bf16
__global__ void castk(const float* __restrict__ in, __hip_bfloat16* __restrict__ out, int n4) {
    int i = blockIdx.x * 256 + threadIdx.x;
    if (i < n4) {
        float4 v = *(const float4*)(in + (size_t)i * 4);
        out[(size_t)i*4 + 0] = __float2bfloat16(v.x);
        out[(size_t)i*4 + 1] = __float2bfloat16(v.y);
        out[(size_t)i*4 + 2] = __float2bfloat16(v.z);
        out[(size_t)i*4 + 3] = __float2bfloat16(v.w);
    }
}

__global__ void castw4(const float* __restrict__ w0, const float* __restrict__ w1,
                       const float* __restrict__ w2, const float* __restrict__ w3,
                       __hip_bfloat16* o0, __hip_bfloat16* o1,
                       __hip_bfloat16* o2, __hip_bfloat16* o3, int n4) {
    const float* in; __hip_bfloat16* out;
    switch (blockIdx.y) {
        case 0:  in = w0; out = o0; break;
        case 1:  in = w1; out = o1; break;
        case 2:  in = w2; out = o2; break;
        default: in = w3; out = o3; break;
    }
    int i = blockIdx.x * 256 + threadIdx.x;
    if (i < n4) {
        float4 v = *(const float4*)(in + (size_t)i * 4);
        out[(size_t)i*4 + 0] = __float2bfloat16(v.x);
        out[(size_t)i*4 + 1] = __float2bfloat16(v.y);
        out[(size_t)i*4 + 2] = __float2bfloat16(v.z);
        out[(size_t)i*4 + 3] = __float2bfloat16(v.w);
    }
}

// ---------------------------------------------------------------- NT-GEMM body (m97 structure)
template<int SMEMB, int BF16OUT>
__device__ __forceinline__ void gemm_body(const __hip_bfloat16* __restrict__ Ablk,
                                          const __hip_bfloat16* __restrict__ Wblk,
                                          const float* __restrict__ bias,
                                          void* __restrict__ Cout,
                                          int N, int K, int br, int bc, bool vt)
{
    __shared__ __align__(16) char smem[SMEMB];
    __hip_bfloat16* As = (__hip_bfloat16*)smem;             // 128x32, 8192 B
    __hip_bfloat16* Bs = (__hip_bfloat16*)(smem + 8192);    // 128x32, 8192 B

    const int tid  = threadIdx.x;
    const int wave = tid >> 6, lane = tid & 63;
    const int quad = lane >> 4, l16 = lane & 15;
    const int wr = wave >> 1, wc = wave & 1;

    f32x4 acc[4][4] = {};

    for (int k0 = 0; k0 < K; k0 += 32) {
#pragma unroll
        for (int t = 0; t < 2; ++t) {
            int c = t * 256 + wave * 64 + lane;
            int row = c >> 2, cc = c & 3;
            int base = (t * 256 + wave * 64) * 16;       // wave-uniform
            gload_lds16(Ablk + (size_t)row * K + k0 + cc * 8, (char*)As + base);
            gload_lds16(Wblk + (size_t)row * K + k0 + cc * 8, (char*)Bs + base);
        }
        __syncthreads();

        bf16x8 af[4], bf[4];
#pragma unroll
        for (int i = 0; i < 4; ++i)
            af[i] = *(const bf16x8*)&As[(wr * 64 + i * 16 + l16) * 32 + quad * 8];
#pragma unroll
        for (int j = 0; j < 4; ++j)
            bf[j] = *(const bf16x8*)&Bs[(wc * 64 + j * 16 + l16) * 32 + quad * 8];

#pragma unroll
        for (int i = 0; i < 4; ++i)
#pragma unroll
            for (int j = 0; j < 4; ++j)
                acc[i][j] = __builtin_amdgcn_mfma_f32_16x16x32_bf16(af[i], bf[j], acc[i][j], 0, 0, 0);
        __syncthreads();
    }

    if (BF16OUT && vt) {
        // ---- transposed epilogue: store V^T[(bq*16+bc)*128 + d][s] via LDS 128x136
        __hip_bfloat16* Ls = (__hip_bfloat16*)smem;   // 128*136*2 = 34816 B
#pragma unroll
        for (int j = 0; j < 4; ++j) {
            int d = wc * 64 + j * 16 + l16;
            float bv = bias[bc * 128 + d];
#pragma unroll
            for (int i = 0; i < 4; ++i) {
                int t0 = wr * 64 + i * 16 + quad * 4;
#pragma unroll
                for (int r = 0; r < 4; ++r)
                    Ls[d * 136 + t0 + r] = __float2bfloat16(acc[i][j][r] + bv);
            }
        }
        __syncthreads();
        const int bq = br >> 4;                  // batch
        const int s0 = (br & 15) * 128;          // token offset within batch
        __hip_bfloat16* VT = (__hip_bfloat16*)Cout;
        const size_t rowbase = (size_t)(bq * 16 + bc) * 128;
#pragma unroll
        for (int rep = 0; rep < 8; ++rep) {
            int L = rep * 256 + tid;             // 0..2047
            int d = L >> 4, tch = L & 15;
            bf16x8 v = *(const bf16x8*)&Ls[d * 136 + tch * 8];
            *(bf16x8*)(VT + (rowbase + d) * (size_t)S_ + s0 + tch * 8) = v;
        }
        return;
    }

    // ---- row-major epilogue
#pragma unroll
    for (int i = 0; i < 4; ++i) {
        int row = br * 128 + wr * 64 + i * 16 + quad * 4;
#pragma unroll
        for (int j = 0; j < 4; ++j) {
            int col = bc * 128 + wc * 64 + j * 16 + l16;
            float bv = bias[col];
#pragma unroll
            for (int r = 0; r < 4; ++r) {
                float v = acc[i][j][r] + bv;
                if (BF16OUT)
                    ((__hip_bfloat16*)Cout)[(size_t)(row + r) * N + col] = __float2bfloat16(v);
                else
                    ((float*)Cout)[(size_t)(row + r) * N + col] = v;
            }
        }
    }
}

// fused Q/K/V projection: grid (48, 32); V written transposed per head
__global__ __launch_bounds__(256)
void gemm_qkv(const __hip_bfloat16* __restrict__ X,
              const __hip_bfloat16* __restrict__ Wq, const __hip_bfloat16* __restrict__ Wk,
              const __hip_bfloat16* __restrict__ Wv,
              const float* __restrict__ bq, const float* __restrict__ bk,
              const float* __restrict__ bv,
              __hip_bfloat16* Qo, __hip_bfloat16* Ko, __hip_bfloat16* VTo)
{
    const int sel = blockIdx.x >> 4;     // 0,1,2
    const int bc  = blockIdx.x & 15;
    const int br  = blockIdx.y;
    const __hip_bfloat16* W = (sel == 0) ? Wq : (sel == 1) ? Wk : Wv;
    const float* bias       = (sel == 0) ? bq : (sel == 1) ? bk : bv;
    void* out               = (sel == 0) ? (void*)Qo : (sel == 1) ? (void*)Ko : (void*)VTo;
    gemm_body<34816, 1>(X + (size_t)(br * 128) * H_, W + (size_t)(bc * 128) * H_,
                        bias, out, H_, H_, br, bc, sel == 2);
}

// O-projection: fp32 out
__global__ __launch_bounds__(256)
void gemm_out(const __hip_bfloat16* __restrict__ A, const __hip_bfloat16* __restrict__ W,
              const float* __restrict__ bias, float* __restrict__ C)
{
    gemm_body<16384, 0>(A + (size_t)(blockIdx.y * 128) * H_, W + (size_t)(blockIdx.x * 128) * H_,
                        bias, C, H_, H_, blockIdx.y, blockIdx.x, false);
}

// ---------------------------------------------------------------- flash attention v7
// 1024 blocks (one 64-row q-tile each, LPT-ordered, XCD-pinned), 32 KB LDS
// (single-buffered K + V^T, both pure-DMA), 2 barriers/iter each protecting one buffer.
__global__ __launch_bounds__(256)
void attn_kernel(const __hip_bfloat16* __restrict__ Q,
                 const __hip_bfloat16* __restrict__ K,
                 const __hip_bfloat16* __restrict__ VT,   // [(b*16+h)*128 + d][s]
                 __hip_bfloat16* __restrict__ O)
{
    // 16B-chunk XOR swizzle, DMA-compatible (unpadded), conflict-free b128 reads
    __shared__ __align__(16) char Ks[16384];   // K-tile: 64 key-rows x 256B
    __shared__ __align__(16) char Vt[16384];   // V^T-tile: 128 d-rows x 128B

    const int tid  = threadIdx.x;
    const int wave = tid >> 6, lane = tid & 63;
    const int quad = lane >> 4, l16 = lane & 15;

    // XCD pinning (4 heads/XCD = 4MB K+V = L2) + LPT (heavy q-tiles dispatch first)
    const int lid = blockIdx.x;                  // 0..1023
    const int xcd = lid & 7;
    const int q   = lid >> 3;                    // 0..127
    const int bh  = ((q >> 5) << 3) | xcd;       // 0..31
    const int qb  = 31 - (q & 31);               // descending per head-group
    const int b   = bh >> 4, h = bh & 15;

    const size_t headoff = (size_t)b * S_ * H_ + (size_t)h * HD_;
    const __hip_bfloat16* Qp  = Q + headoff;
    const __hip_bfloat16* Kp  = K + headoff;
    const __hip_bfloat16* Vtp = VT + (size_t)(b * 16 + h) * 128 * S_;

    const float scale = 0.08838834764831843f;    // 1/sqrt(128)
    // bpermute lane addresses for the P C->A transform
    const int A0 = (((quad & 1) * 2) * 16 + l16) * 4;
    const int A1 = A0 + 64;
    const bool hiq = (quad >= 2);

    const int qrow_local = wave * 16;
    const int qrow = qb * 64 + qrow_local;

    bf16x8 qf[4];
#pragma unroll
    for (int kd = 0; kd < 4; ++kd)
        qf[kd] = *(const bf16x8*)(Qp + (size_t)(qrow + l16) * H_ + kd * 32 + quad * 8);

    f32x4 oacc[8] = {};
    float mi = -1e30f, li = 0.0f;                // per-lane: query qrow + l16

    // ---- prologue: DMA tile 0 (K + V^T)
#pragma unroll
    for (int t = 0; t < 4; ++t) {
        int c = wave * 256 + t * 64 + lane;
        int krow = c >> 4, kpos = c & 15;
        gload_lds16(Kp + (size_t)krow * H_ + (kpos ^ (krow & 7)) * 8,
                    &Ks[(wave * 256 + t * 64) * 16]);
        int vrow = c >> 3, vpos = c & 7;
        gload_lds16(Vtp + (size_t)vrow * S_ + (vpos ^ (vrow & 7)) * 8,
                    &Vt[(wave * 256 + t * 64) * 16]);
    }
    __syncthreads();   // drains DMA -> tile 0 ready

    for (int kb = 0; kb <= qb; ++kb) {
        const bool more = (kb < qb);

        // ---- S^T tile: D[key][query] = K·Q^T ; A = K-frag, B = Q-frag
        f32x4 sacc[4] = {};
#pragma unroll
        for (int cb = 0; cb < 4; ++cb) {
#pragma unroll
            for (int kd = 0; kd < 4; ++kd) {
                int row = cb * 16 + l16;
                int pos = (4 * kd + quad) ^ (l16 & 7);
                bf16x8 kf = *(const bf16x8*)&Ks[row * 256 + pos * 16];
                sacc[cb] = __builtin_amdgcn_mfma_f32_16x16x32_bf16(kf, qf[kd], sacc[cb], 0, 0, 0);
            }
        }

        __syncthreads();   // (1) all QK reads of Ks done; also drains last iter's V-DMA

        if (more) {        // async K prefetch into Ks; drained at barrier (2)
            const __hip_bfloat16* Kn = Kp + (size_t)(kb + 1) * 64 * H_;
#pragma unroll
            for (int t = 0; t < 4; ++t) {
                int c = wave * 256 + t * 64 + lane;
                int krow = c >> 4, kpos = c & 15;
                gload_lds16(Kn + (size_t)krow * H_ + (kpos ^ (krow & 7)) * 8,
                            &Ks[(wave * 256 + t * 64) * 16]);
            }
        }

        // lane owns query (qrow + l16); its 16 scores: keys cb*16 + quad*4 + r
        const bool diag = (kb == qb);
        float p[4][4];
        float tm = -1e30f;
#pragma unroll
        for (int cb = 0; cb < 4; ++cb)
#pragma unroll
            for (int r = 0; r < 4; ++r) {
                float s = sacc[cb][r] * scale;
                if (diag) {
                    int keyl = cb * 16 + quad * 4 + r;
                    if (keyl > qrow_local + l16) s = -1e30f;
                }
                p[cb][r] = s;
                tm = fmaxf(tm, s);
            }
        tm = fmaxf(tm, __shfl_xor(tm, 16));
        tm = fmaxf(tm, __shfl_xor(tm, 32));
        float mnew = fmaxf(mi, tm);
        float sum = 0.0f;
#pragma unroll
        for (int cb = 0; cb < 4; ++cb)
#pragma unroll
            for (int r = 0; r < 4; ++r) {
                float e = __expf(p[cb][r] - mnew);
                p[cb][r] = e;
                sum += e;
            }
        sum += __shfl_xor(sum, 16);
        sum += __shfl_xor(sum, 32);
        float alpha = __expf(mi - mnew);
        li = li * alpha + sum;
        mi = mnew;

        // rescale O (C-layout: reg r = query quad*4+r)
        float ar[4];
#pragma unroll
        for (int r = 0; r < 4; ++r)
            ar[r] = __shfl(alpha, quad * 4 + r);
#pragma unroll
        for (int db = 0; db < 8; ++db)
#pragma unroll
            for (int r = 0; r < 4; ++r)
                oacc[db][r] *= ar[r];

        // ---- P C-layout -> A-layout via ds_bpermute
        int Pp[4][2];
#pragma unroll
        for (int cb = 0; cb < 4; ++cb) {
            Pp[cb][0] = packbf(p[cb][0], p[cb][1]);
            Pp[cb][1] = packbf(p[cb][2], p[cb][3]);
        }
        bf16x8 pf[2];
#pragma unroll
        for (int ks = 0; ks < 2; ++ks) {
            int c0 = 2 * ks, c1 = 2 * ks + 1;
            int d0 = __builtin_amdgcn_ds_bpermute(A0, Pp[c0][0]);
            int e0 = __builtin_amdgcn_ds_bpermute(A0, Pp[c1][0]);
            int d1 = __builtin_amdgcn_ds_bpermute(A0, Pp[c0][1]);
            int e1 = __builtin_amdgcn_ds_bpermute(A0, Pp[c1][1]);
            int d2 = __builtin_amdgcn_ds_bpermute(A1, Pp[c0][0]);
            int e2 = __builtin_amdgcn_ds_bpermute(A1, Pp[c1][0]);
            int d3 = __builtin_amdgcn_ds_bpermute(A1, Pp[c0][1]);
            int e3 = __builtin_amdgcn_ds_bpermute(A1, Pp[c1][1]);
            union { int i[4]; bf16x8 v; } u;
            u.i[0] = hiq ? e0 : d0;
            u.i[1] = hiq ? e1 : d1;
            u.i[2] = hiq ? e2 : d2;
            u.i[3] = hiq ? e3 : d3;
            pf[ks] = u.v;
        }

        // ---- O += P @ V : B = V^T frag from swizzled Vt
#pragma unroll
        for (int ks = 0; ks < 2; ++ks) {
#pragma unroll
            for (int db = 0; db < 8; ++db) {
                int vrow = db * 16 + l16;
                int vpos = (ks * 4 + quad) ^ (l16 & 7);
                bf16x8 vf = *(const bf16x8*)&Vt[vrow * 128 + vpos * 16];
                oacc[db] = __builtin_amdgcn_mfma_f32_16x16x32_bf16(pf[ks], vf, oacc[db], 0, 0, 0);
            }
        }

        __syncthreads();   // (2) all PV reads of Vt done; drains K-DMA -> next QK safe

        if (more) {        // async V^T prefetch into Vt; drained at next barrier (1)
            const int vcol = (kb + 1) * 64;
#pragma unroll
            for (int t = 0; t < 4; ++t) {
                int c = wave * 256 + t * 64 + lane;
                int vrow = c >> 3, vpos = c & 7;
                gload_lds16(Vtp + (size_t)vrow * S_ + vcol + (vpos ^ (vrow & 7)) * 8,
                            &Vt[(wave * 256 + t * 64) * 16]);
            }
        }
    }

    // ---- epilogue: O[query=qrow+quad*4+r][d=db*16+l16]
    float lr[4];
#pragma unroll
    for (int r = 0; r < 4; ++r)
        lr[r] = __shfl(li, quad * 4 + r);
#pragma unroll
    for (int db = 0; db < 8; ++db)
#pragma unroll
        for (int r = 0; r < 4; ++r) {
            float v = oacc[db][r] / lr[r];
            size_t row = (size_t)b * S_ + qrow + quad * 4 + r;
            O[row * H_ + h * HD_ + db * 16 + l16] = __float2bfloat16(v);
        }
}

// ---------------------------------------------------------------- launcher
extern "C" void kernel_launch(void* const* d_in, const int* in_sizes, int n_in,
                              void* d_out, int out_size, void* d_ws, size_t ws_size,
                              hipStream_t stream)
{
    const float* hs = (const float*)d_in[0];
    const float* Wq = (const float*)d_in[2];
    const float* bq = (const float*)d_in[3];
    const float* Wk = (const float*)d_in[4];
    const float* bk = (const float*)d_in[5];
    const float* Wv = (const float*)d_in[6];
    const float* bv = (const float*)d_in[7];
    const float* Wo = (const float*)d_in[8];
    const float* bo = (const float*)d_in[9];

    const size_t szX = (size_t)MTOT * H_;
    const size_t szW = (size_t)H_ * H_;

    __hip_bfloat16* Xbf = (__hip_bfloat16*)d_ws;   // reused as attention output
    __hip_bfloat16* Wqb = Xbf + szX;
    __hip_bfloat16* Wkb = Wqb + szW;
    __hip_bfloat16* Wvb = Wkb + szW;
    __hip_bfloat16* Wob = Wvb + szW;
    __hip_bfloat16* Qb  = Wob + szW;
    __hip_bfloat16* Kb  = Qb + szX;
    __hip_bfloat16* VTb = Kb + szX;                // V^T [(b*16+h)*128+d][s]

    castk<<<(int)((szX/4 + 255)/256), 256, 0, stream>>>(hs, Xbf, (int)(szX/4));
    dim3 wgrid((unsigned)((szW/4 + 255)/256), 4);
    castw4<<<wgrid, 256, 0, stream>>>(Wq, Wk, Wv, Wo, Wqb, Wkb, Wvb, Wob, (int)(szW/4));

    gemm_qkv<<<dim3(48, 32), 256, 0, stream>>>(Xbf, Wqb, Wkb, Wvb, bq, bk, bv, Qb, Kb, VTb);

    attn_kernel<<<dim3(1024), 256, 0, stream>>>(Qb, Kb, VTb, Xbf);

    gemm_out<<<dim3(16, 32), 256, 0, stream>>>(Xbf, Wob, bo, (float*)d_out);
}